// Round 12
// baseline (137.704 us; speedup 1.0000x reference)
//
#include <hip/hip_runtime.h>
#include <math.h>

// Problem constants (B=8, H=W=32, D=256, heads=4, hd=64)
#define NTOK   1024
#define DMODEL 256
#define NHEADS 4
#define HDIM   64
#define NROWS  8192
#define LOG2E  1.4426950408889634f

typedef __attribute__((ext_vector_type(8))) short          bf16x8;
typedef __attribute__((ext_vector_type(8))) unsigned short ushort8;
typedef __attribute__((ext_vector_type(4))) unsigned short ushort4v;
typedef __attribute__((ext_vector_type(4))) float          f32x4;

__device__ __forceinline__ unsigned short f2bf(float x) {   // RNE fp32->bf16
    unsigned u = __float_as_uint(x);
    u = (u + 0x7fffu + ((u >> 16) & 1u)) >> 16;
    return (unsigned short)u;
}
__device__ __forceinline__ float bf2f(unsigned short u) {
    return __uint_as_float(((unsigned)u) << 16);
}
// pack two fp32 -> two bf16 (truncating) in ONE v_perm_b32
__device__ __forceinline__ unsigned pk_bf2(float lo, float hi) {
    return __builtin_amdgcn_perm(__float_as_uint(hi), __float_as_uint(lo),
                                 0x07060302u);
}

// async global->LDS DMA, 16 B per lane; LDS dest = wave-uniform base + lane*16
#define GLD_LDS16(gp, lp)                                            \
    __builtin_amdgcn_global_load_lds(                                \
        (__attribute__((address_space(1))) void*)(gp),               \
        (__attribute__((address_space(3))) void*)(lp), 16, 0, 0)

// ---------------------------------------------------------------------------
// Kernel 1 (prep): V transpose -> Vt[bh][d][key], x cast -> Xb,
// bias expand Pb3, bf16 pre-cast of Wq/Wk/Wo.  Grid (16, 32) x 256.
// ---------------------------------------------------------------------------
__global__ __launch_bounds__(256) void prep(
    const float* __restrict__ X, unsigned short* __restrict__ Vt,
    unsigned short* __restrict__ Xb,
    const float* __restrict__ bt, float* __restrict__ Pb3,
    const float* __restrict__ Wq, const float* __restrict__ Wk,
    const float* __restrict__ Wo,
    unsigned short* __restrict__ Wqb, unsigned short* __restrict__ Wkb,
    unsigned short* __restrict__ Wob)
{
    const int kt = blockIdx.x;    // 0..15 (64-key tile)
    const int bh = blockIdx.y;    // 0..31
    const int b = bh >> 2, h = bh & 3;
    const int t = threadIdx.x;
    __shared__ unsigned short T[64][80];

    const int gid = (blockIdx.y * gridDim.x + blockIdx.x) * 256 + t;  // 0..131071

    // fused bias expansion (61440 elems)
    if (gid < NHEADS * 15 * 1024) {
        const int w2 = gid & 31;
        const int w1 = (gid >> 5) & 31;
        const int rh = (gid >> 10) % 15;
        const int hh = gid / (15 * 1024);
        int rw = w1 - w2 + 7; rw = rw < 0 ? 0 : (rw > 14 ? 14 : rw);
        Pb3[gid] = bt[(rh * 15 + rw) * NHEADS + hh] * LOG2E;
    }

    // fused weight cast: 3 * 65536 elems = 24576 ushort8 granules
    if (gid < 3 * 8192) {
        const int which = gid >> 13;          // 0=Wq 1=Wk 2=Wo
        const int off   = (gid & 8191) * 8;
        const float* __restrict__ Ws = which == 0 ? Wq : (which == 1 ? Wk : Wo);
        unsigned short* __restrict__ Wd = which == 0 ? Wqb : (which == 1 ? Wkb : Wob);
        const float4 w0 = *(const float4*)&Ws[off];
        const float4 w1 = *(const float4*)&Ws[off + 4];
        ushort8 pk;
        pk[0]=f2bf(w0.x); pk[1]=f2bf(w0.y); pk[2]=f2bf(w0.z); pk[3]=f2bf(w0.w);
        pk[4]=f2bf(w1.x); pk[5]=f2bf(w1.y); pk[6]=f2bf(w1.z); pk[7]=f2bf(w1.w);
        *(ushort8*)&Wd[off] = pk;
    }

    #pragma unroll
    for (int i = 0; i < 4; i++) {
        const int tt  = t + 256 * i;       // 0..1023
        const int key = tt >> 4;           // 0..63
        const int d4  = (tt & 15) * 4;
        const long off = (long)(b*NTOK + kt*64 + key)*DMODEL + h*HDIM + d4;
        const float4 v = *(const float4*)&X[off];
        ushort4v pk;
        pk.x = f2bf(v.x); pk.y = f2bf(v.y); pk.z = f2bf(v.z); pk.w = f2bf(v.w);
        *(ushort4v*)&Xb[off] = pk;          // linear bf16 copy of x
        T[d4+0][key] = pk.x; T[d4+1][key] = pk.y;
        T[d4+2][key] = pk.z; T[d4+3][key] = pk.w;
    }
    __syncthreads();
    #pragma unroll
    for (int i = 0; i < 2; i++) {
        const int tt = t + 256 * i;        // 0..511
        const int d  = tt >> 3;            // 0..63
        const int g  = tt & 7;             // 0..7
        const ushort8 o = *(const ushort8*)&T[d][g*8];
        *(ushort8*)&Vt[(bh*HDIM + d)*NTOK + kt*64 + g*8] = o;
    }
}

// ---------------------------------------------------------------------------
// Kernel 2: FUSED Q+K projection GEMM — each A-frag feeds 8 MFMAs.
// Tile 64(M) x 64(N), 4 waves; Wq+Wk tiles DMA-staged (64 KB LDS).
// ---------------------------------------------------------------------------
__global__ __launch_bounds__(256) void gemm_qk_mfma(
    const unsigned short* __restrict__ Xb,
    const unsigned short* __restrict__ Wqb, const float* __restrict__ bq,
    const unsigned short* __restrict__ Wkb, const float* __restrict__ bk,
    unsigned short* __restrict__ Qb, unsigned short* __restrict__ Kb)
{
    const int n0 = blockIdx.x * 64;
    const int m0 = blockIdx.y * 64;
    const int t  = threadIdx.x;
    const int wv = t >> 6, lane = t & 63;
    const int quad = lane >> 4, l16 = lane & 15;

    __shared__ unsigned short Bs[2][64 * 256];   // 64 KB, swizzled 16B granules

    #pragma unroll
    for (int i = 0; i < 8; i++) {
        const int gr = wv*512 + i*64 + lane;
        const int n  = gr >> 5;
        const int gs = gr & 31;
        const int g  = (gs & 24) | ((gs & 7) ^ (n & 7));
        GLD_LDS16(&Wqb[(n0 + n)*DMODEL + g*8], &Bs[0][(wv*512 + i*64)*8]);
    }
    #pragma unroll
    for (int i = 0; i < 8; i++) {
        const int gr = wv*512 + i*64 + lane;
        const int n  = gr >> 5;
        const int gs = gr & 31;
        const int g  = (gs & 24) | ((gs & 7) ^ (n & 7));
        GLD_LDS16(&Wkb[(n0 + n)*DMODEL + g*8], &Bs[1][(wv*512 + i*64)*8]);
    }
    __syncthreads();

    const int rowbase = m0 + wv * 16;

    f32x4 acc[2][4];
    #pragma unroll
    for (int nf = 0; nf < 4; nf++) {
        const float bvq = bq[n0 + nf*16 + l16];
        const float bvk = bk[n0 + nf*16 + l16];
        acc[0][nf] = (f32x4){bvq,bvq,bvq,bvq};
        acc[1][nf] = (f32x4){bvk,bvk,bvk,bvk};
    }

    for (int ks = 0; ks < 8; ks++) {
        const bf16x8 a0 = *(const bf16x8*)&Xb[(rowbase + l16)*DMODEL + ks*32 + quad*8];
        #pragma unroll
        for (int nf = 0; nf < 4; nf++) {
            const int n = nf*16 + l16;
            const int so = n*256 + 8*((ks*4 + quad) ^ (n & 7));
            const bf16x8 bq8 = *(const bf16x8*)&Bs[0][so];
            const bf16x8 bk8 = *(const bf16x8*)&Bs[1][so];
            acc[0][nf] = __builtin_amdgcn_mfma_f32_16x16x32_bf16(a0, bq8, acc[0][nf], 0, 0, 0);
            acc[1][nf] = __builtin_amdgcn_mfma_f32_16x16x32_bf16(a0, bk8, acc[1][nf], 0, 0, 0);
        }
    }

    const float qscale = 0.125f * LOG2E;
    #pragma unroll
    for (int nf = 0; nf < 4; nf++) {
        const int col = n0 + nf*16 + l16;
        #pragma unroll
        for (int r = 0; r < 4; r++) {
            const int row = rowbase + quad*4 + r;
            Qb[row*DMODEL + col] = f2bf(acc[0][nf][r] * qscale);
            Kb[row*DMODEL + col] = f2bf(acc[1][nf][r]);
        }
    }
}

// ---------------------------------------------------------------------------
// Kernel 3: MFMA flash attention, 32-row wave tiles, split-K=4.
// Grid (8 qtiles of 128, 32 bh, 4 quarters) = 1024 blocks, 256 thr.
// Each ka/vb LDS read feeds TWO MFMAs (row-groups rg=0,1):
//   LDS reads/MFMA = 20/32 = 0.63 (was 1.1).
// K,V double-buffered async-DMA (8 KB tiles); Ps 16 KB.  LDS 48 KB -> 3/CU.
// P packed via 1-instr v_perm truncation.  Unnormalized partial O + sums.
// ---------------------------------------------------------------------------
__global__ __launch_bounds__(256, 3) void attn_mfma(
    const unsigned short* __restrict__ Qb, const unsigned short* __restrict__ Kb,
    const unsigned short* __restrict__ Vt, const float* __restrict__ Pb3,
    unsigned short* __restrict__ Op, float* __restrict__ rsum)
{
    const int qt   = blockIdx.x;    // 0..7
    const int bh   = blockIdx.y;    // 0..31
    const int qr   = blockIdx.z;    // 0..3 (key quarter)
    const int b    = bh >> 2, h = bh & 3;
    const int t    = threadIdx.x;
    const int wv   = t >> 6, lane = t & 63;
    const int quad = lane >> 4, l16 = lane & 15;

    __shared__ unsigned short Ks[2][64 * 64];   // 16 KB
    __shared__ unsigned short Vs[2][64 * 64];   // 16 KB
    __shared__ unsigned short Ps[4][32 * 64];   // 16 KB, XOR-swizzled

    const int qbase = qt * 128 + wv * 32;       // 32-aligned
    const int h1    = qbase >> 5;               // wave-uniform (32 rows same h1)

    // Q A/B-fragments for both row-groups (rows qbase+rg*16+l16)
    bf16x8 qa[2][2];
    #pragma unroll
    for (int rg = 0; rg < 2; rg++) {
        const unsigned short* qp =
            &Qb[(b*NTOK + qbase + rg*16 + l16) * DMODEL + h*HDIM + quad*8];
        qa[rg][0] = *(const bf16x8*)(qp);
        qa[rg][1] = *(const bf16x8*)(qp + 32);
    }

    f32x4 Of[2][4] = {};
    float rs[2] = {};

    const unsigned short* KbBase = &Kb[(b*NTOK) * DMODEL + h*HDIM];
    const unsigned short* VtBase = &Vt[(bh*HDIM) * NTOK];
    unsigned short* Pw = Ps[wv];
    const int cbase = qr * 256;

    // async-DMA a 64-key K+V chunk into buffer pb (swizzle via permuted column)
    auto stage = [&](int c0, int pb) {
        #pragma unroll
        for (int i = 0; i < 2; i++) {
            const int gr  = wv*128 + i*64 + lane;   // 0..511
            const int key = gr >> 3, gs = gr & 7;
            const int g   = gs ^ (key & 7);
            GLD_LDS16(&KbBase[(c0 + key)*DMODEL + g*8], &Ks[pb][(wv*128 + i*64)*8]);
        }
        #pragma unroll
        for (int i = 0; i < 2; i++) {
            const int gr = wv*128 + i*64 + lane;
            const int d  = gr >> 3, gs = gr & 7;
            const int gk = gs ^ (d & 7);
            GLD_LDS16(&VtBase[d*NTOK + c0 + gk*8], &Vs[pb][(wv*128 + i*64)*8]);
        }
    };

    stage(cbase, 0);
    __syncthreads();          // drains vmcnt -> chunk 0 resident

    for (int ch = 0; ch < 4; ch++) {
        const int c0 = cbase + ch * 64;
        const int p  = ch & 1;

        // async DMA for chunk ch+1 into the back buffer
        if (ch < 3) stage(c0 + 64, p ^ 1);

        // bias loads up-front: [nt][rg], w1 = rg*16 + l16 (qbase is 32-aligned)
        f32x4 bias_c[4][2];
        #pragma unroll
        for (int nt = 0; nt < 4; nt++) {
            const int nk = c0 + nt*16;
            const int h2 = nk >> 5;
            int rh = h1 - h2 + 7; rh = rh < 0 ? 0 : (rh > 14 ? 14 : rh);
            const int w2b = (nk & 31) + quad*4;
            const float* bp = &Pb3[((h*15 + rh)*32)*32 + w2b];
            bias_c[nt][0] = *(const f32x4*)&bp[(      l16)*32];
            bias_c[nt][1] = *(const f32x4*)&bp[(16 +  l16)*32];
        }

        // ---- scores: S^T = K_tile @ Q^T; each ka feeds both row-groups ----
        #pragma unroll
        for (int nt = 0; nt < 4; nt++) {
            const int kk = nt*16 + l16;
            const bf16x8 ka0 = *(const bf16x8*)&Ks[p][kk*64 + 8*( quad      ^ (kk & 7))];
            const bf16x8 ka1 = *(const bf16x8*)&Ks[p][kk*64 + 8*((quad + 4) ^ (kk & 7))];
            #pragma unroll
            for (int rg = 0; rg < 2; rg++) {
                f32x4 c = bias_c[nt][rg];
                c = __builtin_amdgcn_mfma_f32_16x16x32_bf16(ka0, qa[rg][0], c, 0, 0, 0);
                c = __builtin_amdgcn_mfma_f32_16x16x32_bf16(ka1, qa[rg][1], c, 0, 0, 0);
                const float p0 = exp2f(c[0]), p1 = exp2f(c[1]);
                const float p2 = exp2f(c[2]), p3 = exp2f(c[3]);
                rs[rg] += (p0 + p1) + (p2 + p3);
                uint2 pk;
                pk.x = pk_bf2(p0, p1);     // truncating bf16 pair-pack (1 instr)
                pk.y = pk_bf2(p2, p3);
                // P store: row = rg*16+l16, keys nt*16+quad*4..+3
                const int g = nt*2 + (quad >> 1);
                *(uint2*)&Pw[(rg*16 + l16)*64 + 8*(g ^ (l16 & 7)) + (quad & 1)*4] = pk;
            }
        }
        // same-wave P write->read: DS pipe is in-order per wave; pin ordering
        __builtin_amdgcn_wave_barrier();

        // ---- PV: O += P V ; each vb feeds both row-groups ----
        #pragma unroll
        for (int ks = 0; ks < 2; ks++) {
            bf16x8 pa[2];
            #pragma unroll
            for (int rg = 0; rg < 2; rg++)
                pa[rg] = *(const bf16x8*)
                    &Pw[(rg*16 + l16)*64 + 8*((ks*4 + quad) ^ (l16 & 7))];
            #pragma unroll
            for (int dt = 0; dt < 4; dt++) {
                const int dcol = dt*16 + l16;
                const bf16x8 vb = *(const bf16x8*)
                    &Vs[p][dcol*64 + 8*((ks*4 + quad) ^ (dcol & 7))];
                Of[0][dt] = __builtin_amdgcn_mfma_f32_16x16x32_bf16(pa[0], vb, Of[0][dt], 0, 0, 0);
                Of[1][dt] = __builtin_amdgcn_mfma_f32_16x16x32_bf16(pa[1], vb, Of[1][dt], 0, 0, 0);
            }
        }

        // all waves done with buf p; ch+1 DMA drained (vmcnt(0) before barrier)
        if (ch < 3) __syncthreads();
    }

    // ---- epilogue: partial row sums + unnormalized bf16 partial O ----
    #pragma unroll
    for (int rg = 0; rg < 2; rg++) {
        float tot = rs[rg];
        tot += __shfl_xor(tot, 16);
        tot += __shfl_xor(tot, 32);      // all quads hold sum for row rg*16+l16
        if (quad == 0)
            rsum[(qr*32 + bh)*NTOK + qbase + rg*16 + l16] = tot;
        #pragma unroll
        for (int dt = 0; dt < 4; dt++)
            #pragma unroll
            for (int r = 0; r < 4; r++) {
                const int row = qbase + rg*16 + quad*4 + r;
                Op[((long)qr*NROWS + b*NTOK + row)*DMODEL + h*HDIM + dt*16 + l16]
                    = f2bf(Of[rg][dt][r]);
            }
    }
}

// ---------------------------------------------------------------------------
// Kernel 4: MFMA output projection + gated blend with FUSED 4-way split-K
// combine: A-frag = (Op0+Op1+Op2+Op3) * rinv[head] built in-register.
// out = x + (1-g)*pe + g*(O @ Wo^T + bo), fp32 out.  64x64 tile, 512 blocks.
// ---------------------------------------------------------------------------
__global__ __launch_bounds__(256) void gemm_out_mfma(
    const unsigned short* __restrict__ Op, const float* __restrict__ rsum,
    const unsigned short* __restrict__ Wob, const float* __restrict__ bo,
    const float* __restrict__ X, const float* __restrict__ PE,
    const float* __restrict__ gatep,
    float* __restrict__ Out)
{
    const int n0 = blockIdx.x * 64;
    const int m0 = blockIdx.y * 64;
    const int t  = threadIdx.x;
    const int wv = t >> 6, lane = t & 63;
    const int quad = lane >> 4, l16 = lane & 15;

    __shared__ unsigned short Bs[64 * 256];

    #pragma unroll
    for (int i = 0; i < 8; i++) {
        const int gr = wv*512 + i*64 + lane;
        const int n  = gr >> 5;
        const int gs = gr & 31;
        const int g  = (gs & 24) | ((gs & 7) ^ (n & 7));
        GLD_LDS16(&Wob[(n0 + n)*DMODEL + g*8], &Bs[(wv*512 + i*64)*8]);
    }
    __syncthreads();

    const int rowbase = m0 + wv * 16;
    const int arow = rowbase + l16;          // this lane's A row
    const int ab = arow >> 10, an = arow & 1023;

    // per-head 1/(l0+l1+l2+l3) for this row
    float rinv4[4];
    #pragma unroll
    for (int hh = 0; hh < 4; hh++) {
        float s = 0.f;
        #pragma unroll
        for (int q = 0; q < 4; q++)
            s += rsum[((q*32) + ab*NHEADS + hh)*NTOK + an];
        rinv4[hh] = 1.0f / s;
    }

    f32x4 acc[4];
    #pragma unroll
    for (int nf = 0; nf < 4; nf++) {
        const float bv = bo[n0 + nf*16 + l16];
        acc[nf] = (f32x4){bv,bv,bv,bv};
    }

    for (int ks = 0; ks < 8; ks++) {
        const float ri = rinv4[ks >> 1];     // head = (ks*32)/64
        const long aoff = (long)arow*DMODEL + ks*32 + quad*8;
        const ushort8 p0 = *(const ushort8*)&Op[aoff];
        const ushort8 p1 = *(const ushort8*)&Op[(long)NROWS*DMODEL   + aoff];
        const ushort8 p2 = *(const ushort8*)&Op[(long)NROWS*DMODEL*2 + aoff];
        const ushort8 p3 = *(const ushort8*)&Op[(long)NROWS*DMODEL*3 + aoff];
        bf16x8 a0;
        #pragma unroll
        for (int j = 0; j < 8; j++)
            a0[j] = (short)f2bf(((bf2f(p0[j]) + bf2f(p1[j]))
                               + (bf2f(p2[j]) + bf2f(p3[j]))) * ri);
        #pragma unroll
        for (int nf = 0; nf < 4; nf++) {
            const int n = nf*16 + l16;
            const bf16x8 bfr = *(const bf16x8*)&Bs[n*256 + 8*((ks*4 + quad) ^ (n & 7))];
            acc[nf] = __builtin_amdgcn_mfma_f32_16x16x32_bf16(a0, bfr, acc[nf], 0, 0, 0);
        }
    }

    const float g  = 1.f / (1.f + __expf(-gatep[0]));
    const float og = 1.f - g;

    #pragma unroll
    for (int nf = 0; nf < 4; nf++) {
        const int col = n0 + nf*16 + l16;
        #pragma unroll
        for (int r = 0; r < 4; r++) {
            const int row = rowbase + quad*4 + r;
            const float xv  = X [row*DMODEL + col];
            const float pev = PE[row*DMODEL + col];
            Out[row*DMODEL + col] = xv + og * pev + g * acc[nf][r];
        }
    }
}

// ---------------------------------------------------------------------------
extern "C" void kernel_launch(void* const* d_in, const int* in_sizes, int n_in,
                              void* d_out, int out_size, void* d_ws, size_t ws_size,
                              hipStream_t stream)
{
    const float* x    = (const float*)d_in[0];
    const float* pe   = (const float*)d_in[1];
    const float* Wq   = (const float*)d_in[2];
    const float* bq   = (const float*)d_in[3];
    const float* Wk   = (const float*)d_in[4];
    const float* bk   = (const float*)d_in[5];
    const float* Wo   = (const float*)d_in[6];
    const float* bo   = (const float*)d_in[7];
    const float* bt   = (const float*)d_in[8];
    const float* gate = (const float*)d_in[9];
    float* out = (float*)d_out;

    char* w = (char*)d_ws;
    const size_t MB = 1024u*1024u;
    unsigned short* Qb  = (unsigned short*)(w);               // 4 MB
    unsigned short* Kb  = (unsigned short*)(w + 4*MB);        // 4 MB
    unsigned short* Vtb = (unsigned short*)(w + 8*MB);        // 4 MB
    unsigned short* Xb  = (unsigned short*)(w + 12*MB);       // 4 MB
    float*          Pb3 = (float*)(w + 16*MB);                // 240 KB (rsvd 256K)
    unsigned short* Wqb = (unsigned short*)(w + 16*MB + 256u*1024);  // 128 KB
    unsigned short* Wkb = (unsigned short*)(w + 16*MB + 384u*1024);  // 128 KB
    unsigned short* Wob = (unsigned short*)(w + 16*MB + 512u*1024);  // 128 KB
    float*          rsum= (float*)(w + 16*MB + 640u*1024);           // 512 KB
    unsigned short* Op  = (unsigned short*)(w + 18*MB);       // 16 MB (4 quarters)

    prep<<<dim3(16, 32), 256, 0, stream>>>(
        x, Vtb, Xb, bt, Pb3, Wq, Wk, Wo, Wqb, Wkb, Wob);

    gemm_qk_mfma<<<dim3(DMODEL/64, NROWS/64), 256, 0, stream>>>(
        Xb, Wqb, bq, Wkb, bk, Qb, Kb);

    attn_mfma<<<dim3(8, 32, 4), 256, 0, stream>>>(
        Qb, Kb, Vtb, Pb3, Op, rsum);

    gemm_out_mfma<<<dim3(DMODEL/64, NROWS/64), 256, 0, stream>>>(
        Op, rsum, Wob, bo, x, pe, gate, out);
}

// Round 13
// 128.855 us; speedup vs baseline: 1.0687x; 1.0687x over previous
//
#include <hip/hip_runtime.h>
#include <math.h>

// Problem constants (B=8, H=W=32, D=256, heads=4, hd=64)
#define NTOK   1024
#define DMODEL 256
#define NHEADS 4
#define HDIM   64
#define NROWS  8192
#define LOG2E  1.4426950408889634f

typedef __attribute__((ext_vector_type(8))) short          bf16x8;
typedef __attribute__((ext_vector_type(8))) unsigned short ushort8;
typedef __attribute__((ext_vector_type(4))) unsigned short ushort4v;
typedef __attribute__((ext_vector_type(4))) float          f32x4;

__device__ __forceinline__ unsigned short f2bf(float x) {   // RNE fp32->bf16
    unsigned u = __float_as_uint(x);
    u = (u + 0x7fffu + ((u >> 16) & 1u)) >> 16;
    return (unsigned short)u;
}
__device__ __forceinline__ float bf2f(unsigned short u) {
    return __uint_as_float(((unsigned)u) << 16);
}
// pack two fp32 -> two bf16 (truncating) in ONE v_perm_b32
__device__ __forceinline__ unsigned pk_bf2(float lo, float hi) {
    return __builtin_amdgcn_perm(__float_as_uint(hi), __float_as_uint(lo),
                                 0x07060302u);
}

// async global->LDS DMA, 16 B per lane; LDS dest = wave-uniform base + lane*16
#define GLD_LDS16(gp, lp)                                            \
    __builtin_amdgcn_global_load_lds(                                \
        (__attribute__((address_space(1))) void*)(gp),               \
        (__attribute__((address_space(3))) void*)(lp), 16, 0, 0)

// ---------------------------------------------------------------------------
// Kernel 1 (prep): V transpose -> Vt[bh][d][key], x cast -> Xb,
// bias expand Pb3, bf16 pre-cast of Wq/Wk/Wo.  Grid (16, 32) x 256.
// ---------------------------------------------------------------------------
__global__ __launch_bounds__(256) void prep(
    const float* __restrict__ X, unsigned short* __restrict__ Vt,
    unsigned short* __restrict__ Xb,
    const float* __restrict__ bt, float* __restrict__ Pb3,
    const float* __restrict__ Wq, const float* __restrict__ Wk,
    const float* __restrict__ Wo,
    unsigned short* __restrict__ Wqb, unsigned short* __restrict__ Wkb,
    unsigned short* __restrict__ Wob)
{
    const int kt = blockIdx.x;    // 0..15 (64-key tile)
    const int bh = blockIdx.y;    // 0..31
    const int b = bh >> 2, h = bh & 3;
    const int t = threadIdx.x;
    __shared__ unsigned short T[64][80];

    const int gid = (blockIdx.y * gridDim.x + blockIdx.x) * 256 + t;  // 0..131071

    // fused bias expansion (61440 elems)
    if (gid < NHEADS * 15 * 1024) {
        const int w2 = gid & 31;
        const int w1 = (gid >> 5) & 31;
        const int rh = (gid >> 10) % 15;
        const int hh = gid / (15 * 1024);
        int rw = w1 - w2 + 7; rw = rw < 0 ? 0 : (rw > 14 ? 14 : rw);
        Pb3[gid] = bt[(rh * 15 + rw) * NHEADS + hh] * LOG2E;
    }

    // fused weight cast: 3 * 65536 elems = 24576 ushort8 granules
    if (gid < 3 * 8192) {
        const int which = gid >> 13;          // 0=Wq 1=Wk 2=Wo
        const int off   = (gid & 8191) * 8;
        const float* __restrict__ Ws = which == 0 ? Wq : (which == 1 ? Wk : Wo);
        unsigned short* __restrict__ Wd = which == 0 ? Wqb : (which == 1 ? Wkb : Wob);
        const float4 w0 = *(const float4*)&Ws[off];
        const float4 w1 = *(const float4*)&Ws[off + 4];
        ushort8 pk;
        pk[0]=f2bf(w0.x); pk[1]=f2bf(w0.y); pk[2]=f2bf(w0.z); pk[3]=f2bf(w0.w);
        pk[4]=f2bf(w1.x); pk[5]=f2bf(w1.y); pk[6]=f2bf(w1.z); pk[7]=f2bf(w1.w);
        *(ushort8*)&Wd[off] = pk;
    }

    #pragma unroll
    for (int i = 0; i < 4; i++) {
        const int tt  = t + 256 * i;       // 0..1023
        const int key = tt >> 4;           // 0..63
        const int d4  = (tt & 15) * 4;
        const long off = (long)(b*NTOK + kt*64 + key)*DMODEL + h*HDIM + d4;
        const float4 v = *(const float4*)&X[off];
        ushort4v pk;
        pk.x = f2bf(v.x); pk.y = f2bf(v.y); pk.z = f2bf(v.z); pk.w = f2bf(v.w);
        *(ushort4v*)&Xb[off] = pk;          // linear bf16 copy of x
        T[d4+0][key] = pk.x; T[d4+1][key] = pk.y;
        T[d4+2][key] = pk.z; T[d4+3][key] = pk.w;
    }
    __syncthreads();
    #pragma unroll
    for (int i = 0; i < 2; i++) {
        const int tt = t + 256 * i;        // 0..511
        const int d  = tt >> 3;            // 0..63
        const int g  = tt & 7;             // 0..7
        const ushort8 o = *(const ushort8*)&T[d][g*8];
        *(ushort8*)&Vt[(bh*HDIM + d)*NTOK + kt*64 + g*8] = o;
    }
}

// ---------------------------------------------------------------------------
// Kernel 2: FUSED Q+K projection GEMM — each A-frag feeds 8 MFMAs.
// Tile 64(M) x 64(N), 4 waves; Wq+Wk tiles DMA-staged (64 KB LDS, 2/CU,
// grid 512 = exactly one round).
// ---------------------------------------------------------------------------
__global__ __launch_bounds__(256) void gemm_qk_mfma(
    const unsigned short* __restrict__ Xb,
    const unsigned short* __restrict__ Wqb, const float* __restrict__ bq,
    const unsigned short* __restrict__ Wkb, const float* __restrict__ bk,
    unsigned short* __restrict__ Qb, unsigned short* __restrict__ Kb)
{
    const int n0 = blockIdx.x * 64;
    const int m0 = blockIdx.y * 64;
    const int t  = threadIdx.x;
    const int wv = t >> 6, lane = t & 63;
    const int quad = lane >> 4, l16 = lane & 15;

    __shared__ unsigned short Bs[2][64 * 256];   // 64 KB, swizzled 16B granules

    #pragma unroll
    for (int i = 0; i < 8; i++) {
        const int gr = wv*512 + i*64 + lane;
        const int n  = gr >> 5;
        const int gs = gr & 31;
        const int g  = (gs & 24) | ((gs & 7) ^ (n & 7));
        GLD_LDS16(&Wqb[(n0 + n)*DMODEL + g*8], &Bs[0][(wv*512 + i*64)*8]);
    }
    #pragma unroll
    for (int i = 0; i < 8; i++) {
        const int gr = wv*512 + i*64 + lane;
        const int n  = gr >> 5;
        const int gs = gr & 31;
        const int g  = (gs & 24) | ((gs & 7) ^ (n & 7));
        GLD_LDS16(&Wkb[(n0 + n)*DMODEL + g*8], &Bs[1][(wv*512 + i*64)*8]);
    }
    __syncthreads();

    const int rowbase = m0 + wv * 16;

    f32x4 acc[2][4];
    #pragma unroll
    for (int nf = 0; nf < 4; nf++) {
        const float bvq = bq[n0 + nf*16 + l16];
        const float bvk = bk[n0 + nf*16 + l16];
        acc[0][nf] = (f32x4){bvq,bvq,bvq,bvq};
        acc[1][nf] = (f32x4){bvk,bvk,bvk,bvk};
    }

    for (int ks = 0; ks < 8; ks++) {
        const bf16x8 a0 = *(const bf16x8*)&Xb[(rowbase + l16)*DMODEL + ks*32 + quad*8];
        #pragma unroll
        for (int nf = 0; nf < 4; nf++) {
            const int n = nf*16 + l16;
            const int so = n*256 + 8*((ks*4 + quad) ^ (n & 7));
            const bf16x8 bq8 = *(const bf16x8*)&Bs[0][so];
            const bf16x8 bk8 = *(const bf16x8*)&Bs[1][so];
            acc[0][nf] = __builtin_amdgcn_mfma_f32_16x16x32_bf16(a0, bq8, acc[0][nf], 0, 0, 0);
            acc[1][nf] = __builtin_amdgcn_mfma_f32_16x16x32_bf16(a0, bk8, acc[1][nf], 0, 0, 0);
        }
    }

    const float qscale = 0.125f * LOG2E;
    #pragma unroll
    for (int nf = 0; nf < 4; nf++) {
        const int col = n0 + nf*16 + l16;
        #pragma unroll
        for (int r = 0; r < 4; r++) {
            const int row = rowbase + quad*4 + r;
            Qb[row*DMODEL + col] = f2bf(acc[0][nf][r] * qscale);
            Kb[row*DMODEL + col] = f2bf(acc[1][nf][r]);
        }
    }
}

// ---------------------------------------------------------------------------
// Kernel 3: MFMA flash attention, split-K=2, 64-key chunks (r11 inner loop).
// Grid (16 qt, 32 bh, 2 halves) = 1024 blocks; LDS 40 KB -> 4 blocks/CU
// -> EXACTLY one full round of resident blocks (no tail quantization).
// K,V double-buffered async-DMA (8 KB tiles); Ps 8 KB XOR-swizzled.
// P packed via 1-instr v_perm truncation.  Unnormalized partial O + sums.
// ---------------------------------------------------------------------------
__global__ __launch_bounds__(256, 4) void attn_mfma(
    const unsigned short* __restrict__ Qb, const unsigned short* __restrict__ Kb,
    const unsigned short* __restrict__ Vt, const float* __restrict__ Pb3,
    unsigned short* __restrict__ Op, float* __restrict__ rsum)
{
    const int qt   = blockIdx.x;    // 0..15
    const int bh   = blockIdx.y;    // 0..31
    const int qr   = blockIdx.z;    // 0..1 (key half)
    const int b    = bh >> 2, h = bh & 3;
    const int t    = threadIdx.x;
    const int wv   = t >> 6, lane = t & 63;
    const int quad = lane >> 4, l16 = lane & 15;

    __shared__ unsigned short Ks[2][64 * 64];   // 16 KB
    __shared__ unsigned short Vs[2][64 * 64];   // 16 KB
    __shared__ unsigned short Ps[4][16 * 64];   // 8 KB, XOR-swizzled

    const int qbase = qt * 64 + wv * 16;
    const int h1    = qbase >> 5;               // wave-uniform
    const int w1    = (qbase & 31) + l16;

    bf16x8 qa0, qa1;
    {
        const unsigned short* qp =
            &Qb[(b*NTOK + qbase + l16) * DMODEL + h*HDIM + quad*8];
        qa0 = *(const bf16x8*)(qp);
        qa1 = *(const bf16x8*)(qp + 32);
    }

    f32x4 Of[4] = {};
    float rs = 0.f;

    const unsigned short* KbBase = &Kb[(b*NTOK) * DMODEL + h*HDIM];
    const unsigned short* VtBase = &Vt[(bh*HDIM) * NTOK];
    unsigned short* Pw = Ps[wv];
    const int cbase = qr * 512;

    // async-DMA a 64-key K+V chunk into buffer pb (swizzle via permuted column)
    auto stage = [&](int c0, int pb) {
        #pragma unroll
        for (int i = 0; i < 2; i++) {
            const int gr  = wv*128 + i*64 + lane;   // 0..511
            const int key = gr >> 3, gs = gr & 7;
            const int g   = gs ^ (key & 7);
            GLD_LDS16(&KbBase[(c0 + key)*DMODEL + g*8], &Ks[pb][(wv*128 + i*64)*8]);
        }
        #pragma unroll
        for (int i = 0; i < 2; i++) {
            const int gr = wv*128 + i*64 + lane;
            const int d  = gr >> 3, gs = gr & 7;
            const int gk = gs ^ (d & 7);
            GLD_LDS16(&VtBase[d*NTOK + c0 + gk*8], &Vs[pb][(wv*128 + i*64)*8]);
        }
    };

    stage(cbase, 0);
    __syncthreads();          // drains vmcnt -> chunk 0 resident

    for (int ch = 0; ch < 8; ch++) {
        const int c0 = cbase + ch * 64;
        const int p  = ch & 1;

        // async DMA for chunk ch+1 into the back buffer
        if (ch < 7) stage(c0 + 64, p ^ 1);

        // issue the 4 bias loads for this chunk up-front
        f32x4 bias_c[4];
        #pragma unroll
        for (int nt = 0; nt < 4; nt++) {
            const int nk = c0 + nt*16;
            const int h2 = nk >> 5;
            int rh = h1 - h2 + 7; rh = rh < 0 ? 0 : (rh > 14 ? 14 : rh);
            bias_c[nt] = *(const f32x4*)
                &Pb3[(((h*15 + rh)*32) + w1)*32 + (nk & 31) + quad*4];
        }

        // ---- scores: S^T tile = K_tile @ Q^T, bias preloaded in acc ----
        #pragma unroll
        for (int nt = 0; nt < 4; nt++) {
            f32x4 c = bias_c[nt];
            const int kk = nt*16 + l16;
            {
                const bf16x8 ka = *(const bf16x8*)&Ks[p][kk*64 + 8*(quad ^ (kk & 7))];
                c = __builtin_amdgcn_mfma_f32_16x16x32_bf16(ka, qa0, c, 0, 0, 0);
            }
            {
                const bf16x8 ka = *(const bf16x8*)&Ks[p][kk*64 + 8*((quad+4) ^ (kk & 7))];
                c = __builtin_amdgcn_mfma_f32_16x16x32_bf16(ka, qa1, c, 0, 0, 0);
            }
            const float p0 = exp2f(c[0]), p1 = exp2f(c[1]);
            const float p2 = exp2f(c[2]), p3 = exp2f(c[3]);
            rs += (p0 + p1) + (p2 + p3);
            uint2 pk;
            pk.x = pk_bf2(p0, p1);     // truncating bf16 pair-pack (1 instr)
            pk.y = pk_bf2(p2, p3);
            // P store: row=qrow=l16, keys nt*16+quad*4..+3 (swizzled granule)
            const int g = nt*2 + (quad >> 1);
            *(uint2*)&Pw[l16*64 + 8*(g ^ (l16 & 7)) + (quad & 1)*4] = pk;
        }
        // same-wave P write->read: DS pipe is in-order per wave; pin ordering
        __builtin_amdgcn_wave_barrier();

        // ---- PV: O += P V ----
        #pragma unroll
        for (int ks = 0; ks < 2; ks++) {
            const bf16x8 pa = *(const bf16x8*)&Pw[l16*64 + 8*((ks*4 + quad) ^ (l16 & 7))];
            #pragma unroll
            for (int dt = 0; dt < 4; dt++) {
                const int dcol = dt*16 + l16;
                const bf16x8 vb = *(const bf16x8*)
                    &Vs[p][dcol*64 + 8*((ks*4 + quad) ^ (dcol & 7))];
                Of[dt] = __builtin_amdgcn_mfma_f32_16x16x32_bf16(pa, vb, Of[dt], 0, 0, 0);
            }
        }

        // all waves done with buf p; ch+1 DMA drained (vmcnt(0) before barrier)
        if (ch < 7) __syncthreads();
    }

    // ---- epilogue: partial row sums + unnormalized bf16 partial O ----
    float tot = rs;
    tot += __shfl_xor(tot, 16);
    tot += __shfl_xor(tot, 32);          // full half-sum for q-row l16
    if (quad == 0)
        rsum[(qr*32 + bh)*NTOK + qbase + l16] = tot;

    #pragma unroll
    for (int dt = 0; dt < 4; dt++)
        #pragma unroll
        for (int r = 0; r < 4; r++) {
            const int row = qbase + quad*4 + r;
            Op[((long)qr*NROWS + b*NTOK + row)*DMODEL + h*HDIM + dt*16 + l16]
                = f2bf(Of[dt][r]);
        }
}

// ---------------------------------------------------------------------------
// Kernel 4: MFMA output projection + gated blend with FUSED 2-way split-K
// combine: A-frag = (Op0+Op1) * rinv[head] built in-register.
// out = x + (1-g)*pe + g*(O @ Wo^T + bo), fp32 out.  64x64 tile, 512 blocks.
// ---------------------------------------------------------------------------
__global__ __launch_bounds__(256) void gemm_out_mfma(
    const unsigned short* __restrict__ Op, const float* __restrict__ rsum,
    const unsigned short* __restrict__ Wob, const float* __restrict__ bo,
    const float* __restrict__ X, const float* __restrict__ PE,
    const float* __restrict__ gatep,
    float* __restrict__ Out)
{
    const int n0 = blockIdx.x * 64;
    const int m0 = blockIdx.y * 64;
    const int t  = threadIdx.x;
    const int wv = t >> 6, lane = t & 63;
    const int quad = lane >> 4, l16 = lane & 15;

    __shared__ unsigned short Bs[64 * 256];

    #pragma unroll
    for (int i = 0; i < 8; i++) {
        const int gr = wv*512 + i*64 + lane;
        const int n  = gr >> 5;
        const int gs = gr & 31;
        const int g  = (gs & 24) | ((gs & 7) ^ (n & 7));
        GLD_LDS16(&Wob[(n0 + n)*DMODEL + g*8], &Bs[(wv*512 + i*64)*8]);
    }
    __syncthreads();

    const int rowbase = m0 + wv * 16;
    const int arow = rowbase + l16;          // this lane's A row
    const int ab = arow >> 10, an = arow & 1023;

    // per-head 1/(l0+l1) for this row
    float rinv4[4];
    #pragma unroll
    for (int hh = 0; hh < 4; hh++) {
        const float l0 = rsum[(      ab*NHEADS + hh)*NTOK + an];
        const float l1 = rsum[(32 +  ab*NHEADS + hh)*NTOK + an];
        rinv4[hh] = 1.0f / (l0 + l1);
    }

    f32x4 acc[4];
    #pragma unroll
    for (int nf = 0; nf < 4; nf++) {
        const float bv = bo[n0 + nf*16 + l16];
        acc[nf] = (f32x4){bv,bv,bv,bv};
    }

    for (int ks = 0; ks < 8; ks++) {
        const float ri = rinv4[ks >> 1];     // head = (ks*32)/64
        const long aoff = (long)arow*DMODEL + ks*32 + quad*8;
        const ushort8 p0 = *(const ushort8*)&Op[aoff];
        const ushort8 p1 = *(const ushort8*)&Op[(long)NROWS*DMODEL + aoff];
        bf16x8 a0;
        #pragma unroll
        for (int j = 0; j < 8; j++)
            a0[j] = (short)f2bf((bf2f(p0[j]) + bf2f(p1[j])) * ri);
        #pragma unroll
        for (int nf = 0; nf < 4; nf++) {
            const int n = nf*16 + l16;
            const bf16x8 bfr = *(const bf16x8*)&Bs[n*256 + 8*((ks*4 + quad) ^ (n & 7))];
            acc[nf] = __builtin_amdgcn_mfma_f32_16x16x32_bf16(a0, bfr, acc[nf], 0, 0, 0);
        }
    }

    const float g  = 1.f / (1.f + __expf(-gatep[0]));
    const float og = 1.f - g;

    #pragma unroll
    for (int nf = 0; nf < 4; nf++) {
        const int col = n0 + nf*16 + l16;
        #pragma unroll
        for (int r = 0; r < 4; r++) {
            const int row = rowbase + quad*4 + r;
            const float xv  = X [row*DMODEL + col];
            const float pev = PE[row*DMODEL + col];
            Out[row*DMODEL + col] = xv + og * pev + g * acc[nf][r];
        }
    }
}

// ---------------------------------------------------------------------------
extern "C" void kernel_launch(void* const* d_in, const int* in_sizes, int n_in,
                              void* d_out, int out_size, void* d_ws, size_t ws_size,
                              hipStream_t stream)
{
    const float* x    = (const float*)d_in[0];
    const float* pe   = (const float*)d_in[1];
    const float* Wq   = (const float*)d_in[2];
    const float* bq   = (const float*)d_in[3];
    const float* Wk   = (const float*)d_in[4];
    const float* bk   = (const float*)d_in[5];
    const float* Wo   = (const float*)d_in[6];
    const float* bo   = (const float*)d_in[7];
    const float* bt   = (const float*)d_in[8];
    const float* gate = (const float*)d_in[9];
    float* out = (float*)d_out;

    char* w = (char*)d_ws;
    const size_t MB = 1024u*1024u;
    unsigned short* Qb  = (unsigned short*)(w);               // 4 MB
    unsigned short* Kb  = (unsigned short*)(w + 4*MB);        // 4 MB
    unsigned short* Vtb = (unsigned short*)(w + 8*MB);        // 4 MB
    unsigned short* Xb  = (unsigned short*)(w + 12*MB);       // 4 MB
    float*          Pb3 = (float*)(w + 16*MB);                // 240 KB (rsvd 256K)
    unsigned short* Wqb = (unsigned short*)(w + 16*MB + 256u*1024);  // 128 KB
    unsigned short* Wkb = (unsigned short*)(w + 16*MB + 384u*1024);  // 128 KB
    unsigned short* Wob = (unsigned short*)(w + 16*MB + 512u*1024);  // 128 KB
    float*          rsum= (float*)(w + 16*MB + 640u*1024);           // 256 KB
    unsigned short* Op  = (unsigned short*)(w + 18*MB);       // 8 MB (2 halves)

    prep<<<dim3(16, 32), 256, 0, stream>>>(
        x, Vtb, Xb, bt, Pb3, Wq, Wk, Wo, Wqb, Wkb, Wob);

    gemm_qk_mfma<<<dim3(DMODEL/64, NROWS/64), 256, 0, stream>>>(
        Xb, Wqb, bq, Wkb, bk, Qb, Kb);

    attn_mfma<<<dim3(16, 32, 2), 256, 0, stream>>>(
        Qb, Kb, Vtb, Pb3, Op, rsum);

    gemm_out_mfma<<<dim3(DMODEL/64, NROWS/64), 256, 0, stream>>>(
        Op, rsum, Wob, bo, x, pe, gate, out);
}